// Round 1
// baseline (55.008 us; speedup 1.0000x reference)
//
#include <hip/hip_runtime.h>
#include <cmath>

#define KK 5
#define PAD 2
#define B_ 4
#define CIN 8
#define COUT 16
#define H_ 192
#define W_ 192
#define TW 32
#define TH 32
#define SX (TW + 2 * PAD)   // 36
#define SY (TH + 2 * PAD)   // 36

__global__ __launch_bounds__(256)
void semiconv_kernel(const float* __restrict__ x,
                     const float* __restrict__ scales,
                     float* __restrict__ out) {
    __shared__ float tile[SY][SX];          // 36*36*4 = 5184 B
    __shared__ float wtab[CIN][KK * KK];    // 8*25*4  =  800 B

    int blk = blockIdx.x;
    const int tx_tiles = W_ / TW;  // 6
    const int ty_tiles = H_ / TH;  // 6
    int tile_x = blk % tx_tiles; blk /= tx_tiles;
    int tile_y = blk % ty_tiles; blk /= ty_tiles;
    int co     = blk % COUT;     blk /= COUT;
    int b      = blk;

    const int tid = threadIdx.x;
    const int tx  = tid & 31;     // 0..31 column within tile
    const int ty  = tid >> 5;     // 0..7  base row

    // ---- per-(co,ci) tap weights: w = -(zi^2 + zj^2) * 0.25 / s ----
    if (tid < CIN * KK * KK) {    // 200 threads
        int ci  = tid / (KK * KK);
        int tap = tid % (KK * KK);
        int i = tap / KK, j = tap % KK;
        const float zsq[KK] = {4.f, 1.f, 0.f, 1.f, 4.f};
        float s = scales[co * CIN + ci];
        wtab[ci][tap] = -(zsq[i] + zsq[j]) * 0.25f / s;
    }

    const int gx0 = tile_x * TW - PAD;
    const int gy0 = tile_y * TH - PAD;

    float sum[4] = {0.f, 0.f, 0.f, 0.f};

    for (int ci = 0; ci < CIN; ++ci) {
        __syncthreads();  // wtab ready (iter 0); tile no longer read (iter>0)

        // ---- stage 36x36 halo tile for this ci ----
        const float* xp = x + (size_t)((b * CIN + ci) * H_) * W_;
        for (int idx = tid; idx < SY * SX; idx += 256) {
            int iy = idx / SX, ix = idx % SX;
            int gy = gy0 + iy, gx = gx0 + ix;
            float v = -INFINITY;
            if (gy >= 0 && gy < H_ && gx >= 0 && gx < W_)
                v = xp[gy * W_ + gx];
            tile[iy][ix] = v;
        }
        __syncthreads();

        // ---- 25-tap max-plus, 4 pixels/thread (rows ty, ty+8, ty+16, ty+24) ----
        float m[4] = {-INFINITY, -INFINITY, -INFINITY, -INFINITY};
        #pragma unroll
        for (int i = 0; i < KK; ++i) {
            #pragma unroll
            for (int j = 0; j < KK; ++j) {
                float w = wtab[ci][i * KK + j];
                #pragma unroll
                for (int r = 0; r < 4; ++r) {
                    float v = tile[ty + r * 8 + i][tx + j] + w;
                    m[r] = fmaxf(m[r], v);
                }
            }
        }
        #pragma unroll
        for (int r = 0; r < 4; ++r) sum[r] += m[r];
    }

    float* op = out + ((size_t)(b * COUT + co) * H_ + tile_y * TH) * W_ + tile_x * TW;
    #pragma unroll
    for (int r = 0; r < 4; ++r)
        op[(size_t)(ty + r * 8) * W_ + tx] = sum[r];
}

extern "C" void kernel_launch(void* const* d_in, const int* in_sizes, int n_in,
                              void* d_out, int out_size, void* d_ws, size_t ws_size,
                              hipStream_t stream) {
    const float* x      = (const float*)d_in[0];
    const float* scales = (const float*)d_in[1];
    float* out          = (float*)d_out;

    const int n_blocks = B_ * COUT * (H_ / TH) * (W_ / TW);  // 2304
    semiconv_kernel<<<n_blocks, 256, 0, stream>>>(x, scales, out);
}

// Round 2
// 36.816 us; speedup vs baseline: 1.4941x; 1.4941x over previous
//
#include <hip/hip_runtime.h>
#include <cmath>

#define KK 5
#define PAD 2
#define B_ 4
#define CIN 8
#define COUT 16
#define H_ 192
#define W_ 192
#define TW 32
#define TH 32
#define SX (TW + 2 * PAD)   // 36
#define SY (TH + 2 * PAD)   // 36

__global__ __launch_bounds__(256)
void semiconv_kernel(const float* __restrict__ x,
                     const float* __restrict__ scales,
                     float* __restrict__ out) {
    __shared__ float tile[SY][SX];          // 36*36*4 = 5184 B

    int blk = blockIdx.x;
    const int tx_tiles = W_ / TW;  // 6
    const int ty_tiles = H_ / TH;  // 6
    int tile_x = blk % tx_tiles; blk /= tx_tiles;
    int tile_y = blk % ty_tiles; blk /= ty_tiles;
    int co     = blk % COUT;     blk /= COUT;
    int b      = blk;

    const int tid = threadIdx.x;
    const int tx  = tid & 31;     // 0..31 column within tile
    const int ty2 = tid >> 5;     // 0..7; owns output rows ty2*4 .. ty2*4+3

    const int gx0 = tile_x * TW - PAD;
    const int gy0 = tile_y * TH - PAD;

    float sum[4] = {0.f, 0.f, 0.f, 0.f};

    for (int ci = 0; ci < CIN; ++ci) {
        __syncthreads();  // tile from previous ci no longer read

        // ---- stage 36x36 halo tile for this ci ----
        const float* xp = x + (size_t)((b * CIN + ci) * H_) * W_;
        for (int idx = tid; idx < SY * SX; idx += 256) {
            int iy = idx / SX, ix = idx % SX;
            int gy = gy0 + iy, gx = gx0 + ix;
            float v = -INFINITY;
            if (gy >= 0 && gy < H_ && gx >= 0 && gx < W_)
                v = xp[gy * W_ + gx];
            tile[iy][ix] = v;
        }
        __syncthreads();

        // separable weights: w[i][j] = -(zsq[i]+zsq[j])/(4s), zsq={4,1,0,1,4}
        float s  = scales[co * CIN + ci];
        float a1 = 1.0f / (4.0f * s);
        float a4 = 4.0f * a1;

        // ---- horizontal max-plus pass into registers (8 sliding rows) ----
        float t[8];
        #pragma unroll
        for (int k = 0; k < 8; ++k) {
            const float* row = &tile[ty2 * 4 + k][tx];
            float c0 = row[0], c1 = row[1], c2 = row[2], c3 = row[3], c4 = row[4];
            t[k] = fmaxf(fmaxf(fmaxf(c0 - a4, c4 - a4),
                               fmaxf(c1 - a1, c3 - a1)), c2);
        }
        // ---- vertical max-plus, pure registers ----
        #pragma unroll
        for (int q = 0; q < 4; ++q) {
            float m = fmaxf(fmaxf(fmaxf(t[q] - a4, t[q + 4] - a4),
                                  fmaxf(t[q + 1] - a1, t[q + 3] - a1)), t[q + 2]);
            sum[q] += m;
        }
    }

    float* op = out + ((size_t)(b * COUT + co) * H_ + tile_y * TH + ty2 * 4) * W_
                    + tile_x * TW + tx;
    #pragma unroll
    for (int q = 0; q < 4; ++q)
        op[(size_t)q * W_] = sum[q];
}

extern "C" void kernel_launch(void* const* d_in, const int* in_sizes, int n_in,
                              void* d_out, int out_size, void* d_ws, size_t ws_size,
                              hipStream_t stream) {
    const float* x      = (const float*)d_in[0];
    const float* scales = (const float*)d_in[1];
    float* out          = (float*)d_out;

    const int n_blocks = B_ * COUT * (H_ / TH) * (W_ / TW);  // 2304
    semiconv_kernel<<<n_blocks, 256, 0, stream>>>(x, scales, out);
}

// Round 3
// 23.751 us; speedup vs baseline: 2.3160x; 1.5501x over previous
//
#include <hip/hip_runtime.h>
#include <cmath>

#define B_ 4
#define CIN 8
#define COUT 16
#define H_ 192
#define W_ 192
#define TW 32
#define TH 16
#define PAD 2
#define SX (TW + 2 * PAD)   // 36
#define SY (TH + 2 * PAD)   // 20
#define NCO 8               // output channels per block

__global__ __launch_bounds__(256)
void semiconv_kernel(const float* __restrict__ x,
                     const float* __restrict__ scales,
                     float* __restrict__ out) {
    __shared__ float tile[SY][SX];      // 20*36*4 = 2880 B
    __shared__ float winv[NCO][CIN];    // 256 B

    int blk = blockIdx.x;
    const int tx_tiles = W_ / TW;   // 6
    const int ty_tiles = H_ / TH;   // 12
    int tile_x = blk % tx_tiles; blk /= tx_tiles;
    int tile_y = blk % ty_tiles; blk /= ty_tiles;
    int cg     = blk & 1;        blk >>= 1;   // co-group: 0 or 1
    int b      = blk;

    const int tid = threadIdx.x;
    const int tx  = tid & 31;       // column within tile
    const int ty  = tid >> 5;       // 0..7; owns output rows ty*2, ty*2+1

    // once-per-block weight table: winv[c][ci] = 0.25/s  (a1); a4 = 4*a1
    if (tid < NCO * CIN) {
        int c = tid >> 3, ci = tid & 7;
        winv[c][ci] = 0.25f / scales[(cg * NCO + c) * CIN + ci];
    }

    const int gx0 = tile_x * TW - PAD;
    const int gy0 = tile_y * TH - PAD;

    float sum[NCO][2];
    #pragma unroll
    for (int c = 0; c < NCO; ++c) { sum[c][0] = 0.f; sum[c][1] = 0.f; }

    for (int ci = 0; ci < CIN; ++ci) {
        __syncthreads();  // iter0: winv ready; iter>0: tile no longer read

        // ---- stage 36x20 halo tile for this ci ----
        const float* xp = x + (size_t)((b * CIN + ci) * H_) * W_;
        for (int idx = tid; idx < SY * SX; idx += 256) {
            int iy = idx / SX, ix = idx % SX;
            int gy = gy0 + iy, gx = gx0 + ix;
            float v = -INFINITY;
            if (gy >= 0 && gy < H_ && gx >= 0 && gx < W_)
                v = xp[gy * W_ + gx];
            tile[iy][ix] = v;
        }
        __syncthreads();

        // ---- co-independent row partials: read LDS once, share across 8 co ----
        float m0[6], m1[6], m4[6];
        #pragma unroll
        for (int k = 0; k < 6; ++k) {
            const float* row = &tile[ty * 2 + k][tx];
            float c0 = row[0], c1 = row[1], c2 = row[2], c3 = row[3], c4 = row[4];
            m0[k] = c2;
            m1[k] = fmaxf(c1, c3);
            m4[k] = fmaxf(c0, c4);
        }

        // ---- per-co separable max-plus, pure registers ----
        #pragma unroll
        for (int c = 0; c < NCO; ++c) {
            float a1 = winv[c][ci];      // LDS broadcast (uniform addr)
            float a4 = 4.0f * a1;
            float t[6];
            #pragma unroll
            for (int k = 0; k < 6; ++k)
                t[k] = fmaxf(fmaxf(m1[k] - a1, m4[k] - a4), m0[k]);
            #pragma unroll
            for (int q = 0; q < 2; ++q) {
                float v1 = fmaxf(t[q + 1], t[q + 3]);
                float v4 = fmaxf(t[q],     t[q + 4]);
                sum[c][q] += fmaxf(fmaxf(v1 - a1, v4 - a4), t[q + 2]);
            }
        }
    }

    #pragma unroll
    for (int c = 0; c < NCO; ++c) {
        float* op = out + ((size_t)(b * COUT + cg * NCO + c) * H_
                           + tile_y * TH + ty * 2) * W_ + tile_x * TW + tx;
        op[0]  = sum[c][0];
        op[W_] = sum[c][1];
    }
}

extern "C" void kernel_launch(void* const* d_in, const int* in_sizes, int n_in,
                              void* d_out, int out_size, void* d_ws, size_t ws_size,
                              hipStream_t stream) {
    const float* x      = (const float*)d_in[0];
    const float* scales = (const float*)d_in[1];
    float* out          = (float*)d_out;

    const int n_blocks = B_ * 2 * (H_ / TH) * (W_ / TW);  // 4*2*12*6 = 576
    semiconv_kernel<<<n_blocks, 256, 0, stream>>>(x, scales, out);
}

// Round 4
// 20.902 us; speedup vs baseline: 2.6316x; 1.1363x over previous
//
#include <hip/hip_runtime.h>
#include <cmath>

#define B_ 4
#define CIN 8
#define COUT 16
#define H_ 192
#define W_ 192
#define TW 32
#define TH 16
#define PAD 2
#define SX (TW + 2 * PAD)   // 36
#define SY (TH + 2 * PAD)   // 20
#define NCO 8               // output channels per block
#define TILE_ELEMS (SY * SX)  // 720

__global__ __launch_bounds__(256)
void semiconv_kernel(const float* __restrict__ x,
                     const float* __restrict__ scales,
                     float* __restrict__ out) {
    __shared__ float tile[CIN][SY][SX];   // 8*20*36*4 = 23040 B
    __shared__ float winv[NCO][CIN];      // 256 B

    int blk = blockIdx.x;
    const int tx_tiles = W_ / TW;   // 6
    const int ty_tiles = H_ / TH;   // 12
    int tile_x = blk % tx_tiles; blk /= tx_tiles;
    int tile_y = blk % ty_tiles; blk /= ty_tiles;
    int cg     = blk & 1;        blk >>= 1;   // co-group: 0 or 1
    int b      = blk;

    const int tid = threadIdx.x;
    const int tx  = tid & 31;       // column within tile
    const int ty  = tid >> 5;       // 0..7; owns output rows ty*2, ty*2+1

    // once-per-block weight table: winv[c][ci] = 0.25/s  (a1); a4 = 4*a1
    if (tid < NCO * CIN) {
        int c = tid >> 3, ci = tid & 7;
        winv[c][ci] = 0.25f / scales[(cg * NCO + c) * CIN + ci];
    }

    const int gx0 = tile_x * TW - PAD;
    const int gy0 = tile_y * TH - PAD;

    // ---- precompute staging coords: elements tid, tid+256, tid+512 of 720 ----
    int iyk[3], ixk[3], offk[3];
    bool act[3], okk[3];
    {
        int iy = tid / SX, ix = tid - iy * SX;   // tid < 720 always
        #pragma unroll
        for (int k = 0; k < 3; ++k) {
            iyk[k] = iy; ixk[k] = ix;
            act[k] = (tid + k * 256) < TILE_ELEMS;
            int gy = gy0 + iy, gx = gx0 + ix;
            okk[k] = act[k] && gy >= 0 && gy < H_ && gx >= 0 && gx < W_;
            offk[k] = gy * W_ + gx;
            // advance by 256 = 7*36 + 4
            iy += 7; ix += 4;
            if (ix >= SX) { ix -= SX; iy += 1; }
        }
    }

    // ---- stage ALL 8 ci halo tiles; loads issued back-to-back ----
    const float* xb = x + (size_t)(b * CIN) * H_ * W_;
    #pragma unroll
    for (int ci = 0; ci < CIN; ++ci) {
        const float* xp = xb + (size_t)ci * H_ * W_;
        #pragma unroll
        for (int k = 0; k < 3; ++k) {
            if (act[k]) {
                float v = -INFINITY;
                if (okk[k]) v = xp[offk[k]];
                tile[ci][iyk[k]][ixk[k]] = v;
            }
        }
    }

    __syncthreads();   // the ONLY barrier

    float sum[NCO][2];
    #pragma unroll
    for (int c = 0; c < NCO; ++c) { sum[c][0] = 0.f; sum[c][1] = 0.f; }

    for (int ci = 0; ci < CIN; ++ci) {
        // ---- co-independent row partials: read LDS once, share across 8 co ----
        float m0[6], m1[6], m4[6];
        #pragma unroll
        for (int k = 0; k < 6; ++k) {
            const float* row = &tile[ci][ty * 2 + k][tx];
            float c0 = row[0], c1 = row[1], c2 = row[2], c3 = row[3], c4 = row[4];
            m0[k] = c2;
            m1[k] = fmaxf(c1, c3);
            m4[k] = fmaxf(c0, c4);
        }

        // ---- per-co separable max-plus, pure registers ----
        #pragma unroll
        for (int c = 0; c < NCO; ++c) {
            float a1 = winv[c][ci];      // LDS broadcast (uniform addr)
            float a4 = 4.0f * a1;
            float t[6];
            #pragma unroll
            for (int k = 0; k < 6; ++k)
                t[k] = fmaxf(fmaxf(m1[k] - a1, m4[k] - a4), m0[k]);
            #pragma unroll
            for (int q = 0; q < 2; ++q) {
                float v1 = fmaxf(t[q + 1], t[q + 3]);
                float v4 = fmaxf(t[q],     t[q + 4]);
                sum[c][q] += fmaxf(fmaxf(v1 - a1, v4 - a4), t[q + 2]);
            }
        }
    }

    #pragma unroll
    for (int c = 0; c < NCO; ++c) {
        float* op = out + ((size_t)(b * COUT + cg * NCO + c) * H_
                           + tile_y * TH + ty * 2) * W_ + tile_x * TW + tx;
        op[0]  = sum[c][0];
        op[W_] = sum[c][1];
    }
}

extern "C" void kernel_launch(void* const* d_in, const int* in_sizes, int n_in,
                              void* d_out, int out_size, void* d_ws, size_t ws_size,
                              hipStream_t stream) {
    const float* x      = (const float*)d_in[0];
    const float* scales = (const float*)d_in[1];
    float* out          = (float*)d_out;

    const int n_blocks = B_ * 2 * (H_ / TH) * (W_ / TW);  // 4*2*12*6 = 576
    semiconv_kernel<<<n_blocks, 256, 0, stream>>>(x, scales, out);
}

// Round 5
// 20.888 us; speedup vs baseline: 2.6335x; 1.0007x over previous
//
#include <hip/hip_runtime.h>
#include <cmath>

#define B_ 4
#define CIN 8
#define COUT 16
#define H_ 192
#define W_ 192
#define TW 32
#define TH 16
#define PAD 2
#define SX (TW + 2 * PAD)   // 36
#define SY (TH + 2 * PAD)   // 20
#define NCO 4               // output channels per block (4 co-groups)
#define TILE_ELEMS (SY * SX)  // 720

__global__ __launch_bounds__(256)
void semiconv_kernel(const float* __restrict__ x,
                     const float* __restrict__ scales,
                     float* __restrict__ out) {
    __shared__ float tile[CIN][SY][SX];   // 8*20*36*4 = 23040 B
    __shared__ float winv[NCO][CIN];      // 128 B

    int blk = blockIdx.x;
    const int tx_tiles = W_ / TW;   // 6
    const int ty_tiles = H_ / TH;   // 12
    int tile_x = blk % tx_tiles; blk /= tx_tiles;
    int tile_y = blk % ty_tiles; blk /= ty_tiles;
    int cg     = blk & 3;        blk >>= 2;   // co-group: 0..3
    int b      = blk;

    const int tid = threadIdx.x;
    const int tx  = tid & 31;       // column within tile
    const int ty  = tid >> 5;       // 0..7; owns output rows ty*2, ty*2+1

    // once-per-block weight table: winv[c][ci] = 0.25/s  (a1); a4 = 4*a1
    if (tid < NCO * CIN) {
        int c = tid >> 3, ci = tid & 7;
        winv[c][ci] = 0.25f / scales[(cg * NCO + c) * CIN + ci];
    }

    const int gx0 = tile_x * TW - PAD;
    const int gy0 = tile_y * TH - PAD;

    // ---- precompute staging coords: elements tid, tid+256, tid+512 of 720 ----
    int iyk[3], ixk[3], offk[3];
    bool act[3], okk[3];
    {
        int iy = tid / SX, ix = tid - iy * SX;   // tid < 720 always
        #pragma unroll
        for (int k = 0; k < 3; ++k) {
            iyk[k] = iy; ixk[k] = ix;
            act[k] = (tid + k * 256) < TILE_ELEMS;
            int gy = gy0 + iy, gx = gx0 + ix;
            okk[k] = act[k] && gy >= 0 && gy < H_ && gx >= 0 && gx < W_;
            offk[k] = gy * W_ + gx;
            // advance by 256 = 7*36 + 4
            iy += 7; ix += 4;
            if (ix >= SX) { ix -= SX; iy += 1; }
        }
    }

    // ---- stage ALL 8 ci halo tiles; loads issued back-to-back ----
    const float* xb = x + (size_t)(b * CIN) * H_ * W_;
    #pragma unroll
    for (int ci = 0; ci < CIN; ++ci) {
        const float* xp = xb + (size_t)ci * H_ * W_;
        #pragma unroll
        for (int k = 0; k < 3; ++k) {
            if (act[k]) {
                float v = -INFINITY;
                if (okk[k]) v = xp[offk[k]];
                tile[ci][iyk[k]][ixk[k]] = v;
            }
        }
    }

    __syncthreads();   // the ONLY barrier

    float sum[NCO][2];
    #pragma unroll
    for (int c = 0; c < NCO; ++c) { sum[c][0] = 0.f; sum[c][1] = 0.f; }

    for (int ci = 0; ci < CIN; ++ci) {
        // ---- co-independent row partials: read LDS once, share across co ----
        float m0[6], m1[6], m4[6];
        #pragma unroll
        for (int k = 0; k < 6; ++k) {
            const float* row = &tile[ci][ty * 2 + k][tx];
            float c0 = row[0], c1 = row[1], c2 = row[2], c3 = row[3], c4 = row[4];
            m0[k] = c2;
            m1[k] = fmaxf(c1, c3);
            m4[k] = fmaxf(c0, c4);
        }

        // ---- per-co separable max-plus, pure registers ----
        #pragma unroll
        for (int c = 0; c < NCO; ++c) {
            float a1 = winv[c][ci];      // LDS broadcast (uniform addr)
            float a4 = 4.0f * a1;
            float t[6];
            #pragma unroll
            for (int k = 0; k < 6; ++k)
                t[k] = fmaxf(fmaxf(m1[k] - a1, m4[k] - a4), m0[k]);
            #pragma unroll
            for (int q = 0; q < 2; ++q) {
                float v1 = fmaxf(t[q + 1], t[q + 3]);
                float v4 = fmaxf(t[q],     t[q + 4]);
                sum[c][q] += fmaxf(fmaxf(v1 - a1, v4 - a4), t[q + 2]);
            }
        }
    }

    #pragma unroll
    for (int c = 0; c < NCO; ++c) {
        float* op = out + ((size_t)(b * COUT + cg * NCO + c) * H_
                           + tile_y * TH + ty * 2) * W_ + tile_x * TW + tx;
        op[0]  = sum[c][0];
        op[W_] = sum[c][1];
    }
}

extern "C" void kernel_launch(void* const* d_in, const int* in_sizes, int n_in,
                              void* d_out, int out_size, void* d_ws, size_t ws_size,
                              hipStream_t stream) {
    const float* x      = (const float*)d_in[0];
    const float* scales = (const float*)d_in[1];
    float* out          = (float*)d_out;

    const int n_blocks = B_ * (COUT / NCO) * (H_ / TH) * (W_ / TW);  // 4*4*12*6 = 1152
    semiconv_kernel<<<n_blocks, 256, 0, stream>>>(x, scales, out);
}